// Round 11
// baseline (2736.243 us; speedup 1.0000x reference)
//
#include <hip/hip_runtime.h>
#include <hip/hip_bf16.h>

namespace {

constexpr int kB = 32;
constexpr int kT = 512;
constexpr int kH = 512;
constexpr int kE = 256;
constexpr int kL = 64;
constexpr int kNC = 7 * kH;       // 3584 gate columns
constexpr int kOutRow = 5 * kH;   // 2560
constexpr int kBH = kB * kH;      // 16384 packets per parity slot

typedef float f32x4 __attribute__((ext_vector_type(4)));
typedef short s16x8 __attribute__((ext_vector_type(8)));
typedef __bf16 bf16x8 __attribute__((ext_vector_type(8)));
typedef unsigned int u32x4 __attribute__((ext_vector_type(4)));
typedef unsigned int u32x2 __attribute__((ext_vector_type(2)));

__device__ __forceinline__ unsigned short f2bf(float f) {
  __hip_bfloat16 h = __float2bfloat16(f);
  return __builtin_bit_cast(unsigned short, h);
}

__device__ __forceinline__ float bf2f(unsigned short u) {
  return __builtin_bit_cast(float, (unsigned int)u << 16);
}

// libm versions (setup only)
__device__ __forceinline__ float sigmoid_f(float x) {
  return 1.0f / (1.0f + expf(-x));
}
__device__ __forceinline__ float softplus_f(float x) {
  return fmaxf(x, 0.0f) + log1pf(expf(-fabsf(x)));
}

// fast versions (hot kernel): v_exp_f32 / v_log_f32 / v_rcp_f32
constexpr float kLog2e = 1.4426950408889634f;
constexpr float kLn2 = 0.6931471805599453f;
__device__ __forceinline__ float fexp2(float x) {
  return __builtin_amdgcn_exp2f(x);
}
__device__ __forceinline__ float frcp(float x) {
  return __builtin_amdgcn_rcpf(x);
}
__device__ __forceinline__ float fsigmoid(float x) {
  return frcp(1.0f + fexp2(-x * kLog2e));
}
__device__ __forceinline__ float ftanh(float x) {
  return 1.0f - 2.0f * frcp(1.0f + fexp2((2.0f * kLog2e) * x));
}
__device__ __forceinline__ float fsoftplus(float x) {
  return fmaxf(x, 0.0f) +
         kLn2 * __builtin_amdgcn_logf(1.0f + fexp2(-fabsf(x) * kLog2e));
}

__device__ __forceinline__ f32x4 mfma_bf16(s16x8 a, s16x8 b, f32x4 c) {
  return __builtin_amdgcn_mfma_f32_16x16x32_bf16(
      __builtin_bit_cast(bf16x8, a), __builtin_bit_cast(bf16x8, b), c, 0, 0, 0);
}

__device__ __forceinline__ void st_coh_x2(unsigned int* p, u32x2 v) {
  asm volatile("global_store_dwordx2 %0, %1, off sc0 sc1" :: "v"(p), "v"(v)
               : "memory");
}

__device__ __forceinline__ void unpack(const u32x4& x0, const u32x4& x1,
                                       s16x8& hi, s16x8& lo) {
#pragma unroll
  for (int e = 0; e < 4; ++e) {
    hi[e] = (short)(x0[e] & 0xffffu);
    hi[e + 4] = (short)(x1[e] & 0xffffu);
    lo[e] = (short)(x0[e] >> 16);
    lo[e + 4] = (short)(x1[e] >> 16);
  }
}

// ---------------------------------------------------------------------------
// Setup: emb_part [128][3584], lat_part(+bias) [32][3584], dt [32][512],
// init states -> out row 0, hdtag parity0 = {h0, tag 0}, parity1 poisoned.
// ---------------------------------------------------------------------------
__global__ void hawkes_setup(const float* __restrict__ ts,
                             const float* __restrict__ latent,
                             const float* __restrict__ emb,
                             const float* __restrict__ Wc,
                             const float* __restrict__ bc,
                             const float* __restrict__ Wi,
                             const float* __restrict__ bi,
                             float* __restrict__ out,
                             float* __restrict__ emb_part,
                             float* __restrict__ lat_part,
                             float* __restrict__ dt,
                             float* __restrict__ cd0,
                             float* __restrict__ cb0,
                             unsigned int* __restrict__ hdtag) {
  const int blk = blockIdx.x;
  const int tid = threadIdx.x;
  if (blk < 112) {
    __shared__ float es[16][kE];
    const int cgrp = blk / 14;
    const int col = (blk % 14) * 256 + tid;
    for (int i = tid; i < 16 * kE; i += 256)
      es[i / kE][i % kE] = emb[(cgrp * 16 + i / kE) * kE + (i % kE)];
    __syncthreads();
    float acc[16];
#pragma unroll
    for (int c = 0; c < 16; ++c) acc[c] = 0.0f;
    for (int e = 0; e < kE; ++e) {
      const float w = Wc[(size_t)e * kNC + col];
#pragma unroll
      for (int c = 0; c < 16; ++c) acc[c] = fmaf(es[c][e], w, acc[c]);
    }
#pragma unroll
    for (int c = 0; c < 16; ++c)
      emb_part[(size_t)(cgrp * 16 + c) * kNC + col] = acc[c];
  } else if (blk < 126) {
    __shared__ float ls[kB][kL];
    const int col = (blk - 112) * 256 + tid;
    for (int i = tid; i < kB * kL; i += 256) ls[i / kL][i % kL] = latent[i];
    __syncthreads();
    float acc[kB];
    const float bias = bc[col];
#pragma unroll
    for (int b = 0; b < kB; ++b) acc[b] = bias;
    for (int l = 0; l < kL; ++l) {
      const float w = Wc[(size_t)(kE + l) * kNC + col];
#pragma unroll
      for (int b = 0; b < kB; ++b) acc[b] = fmaf(ls[b][l], w, acc[b]);
    }
#pragma unroll
    for (int b = 0; b < kB; ++b) lat_part[(size_t)b * kNC + col] = acc[b];
  } else if (blk < 222) {
    const int tg = (blk - 126) * 256 + tid;
    for (int it = 0; it < 4; ++it) {
      const int item = tg + it * 24576;
      const int b = item / 3072;
      const int c6 = item % 3072;
      float a = bi[c6];
      for (int l = 0; l < kL; ++l)
        a = fmaf(latent[b * kL + l], Wi[(size_t)l * 3072 + c6], a);
      const int which = c6 >> 9;
      const int jl = c6 & 511;
      float* orow = out + (size_t)b * (kT + 1) * kOutRow;
      if (which == 0) {
        const float h = tanhf(a);
        orow[jl] = h;
        const unsigned int hh = f2bf(h);
        const unsigned int hl = f2bf(h - bf2f((unsigned short)hh));
        u32x2 v0 = {hh | (hl << 16), 0u};
        u32x2 v1 = {0u, 0xFFFFFFFFu};
        st_coh_x2(hdtag + (size_t)(b * kH + jl) * 2, v0);
        st_coh_x2(hdtag + (size_t)(kBH + b * kH + jl) * 2, v1);
      } else if (which == 1) {
        cd0[b * kH + jl] = tanhf(a);
      } else if (which == 2) {
        const float v = tanhf(a);
        orow[2 * kH + jl] = v;
        cb0[b * kH + jl] = v;
      } else if (which == 3) {
        orow[3 * kH + jl] = tanhf(a);
      } else if (which == 4) {
        orow[4 * kH + jl] = softplus_f(a);
      } else {
        orow[kH + jl] = sigmoid_f(a);
      }
    }
  } else {
    const int idx = (blk - 222) * 256 + tid;   // [0,16384)
    const int b = idx >> 9;
    const int t = idx & 511;
    dt[idx] = (t == 0) ? ts[b * kT] : ts[b * kT + t] - ts[b * kT + t - 1];
  }
}

// ---------------------------------------------------------------------------
// Sequential scan (R3-proven structure + pipelined poll): 256 blocks =
// 8 batch-groups (4 batches) x 32 hidden-tiles (16 units). 8 waves x 64;
// wave w owns k-slice [w*64,w*64+64) (weights persistent, bf16 hi/lo).
// Per step:
//   1) PIPELINED tagged cooperative load: 4 idempotent rounds in flight to
//      the same 32B packet group; s_waitcnt vmcnt(6) waits only the oldest
//      round -> rounds land every ~RT/4, detection quantization ~RT/4
//      instead of ~RT (T4 counted-vmcnt applied to spin-polling).
//      Monotone tags (poison -> s-1, never back before our own publish) +
//      in-order load completion make mixed-round samples safe.
//   2) sync; fragment reads, 42 MFMAs, partials -> LDS.
//   3) sync; wave0 reduces, pointwise, publishes {h_d, tag=s} fire-and-forget.
// ---------------------------------------------------------------------------
__global__ __launch_bounds__(512, 2) void hawkes_seq(
    const int* __restrict__ marks, const float* __restrict__ Wc,
    float* __restrict__ out, const float* __restrict__ emb_part,
    const float* __restrict__ lat_part, const float* __restrict__ dt,
    const float* __restrict__ cd0, const float* __restrict__ cb0,
    unsigned int* __restrict__ hdtag) {
  const int blk = blockIdx.x;
  const int bg = blk >> 5;                 // batch group 0..7
  const int jt = blk & 31;                 // hidden tile 0..31
  const int tid = threadIdx.x;
  const int wave = tid >> 6;               // k-slice 0..7
  const int lane = tid & 63;
  const int nl = lane & 15;                // fragment column / A row
  const int kg = lane >> 4;                // k-subgroup 0..3

  __shared__ __align__(16) unsigned int lds_a[4][516];  // packed hi|lo, pad 4
  __shared__ float pl[8][7][16][4];                     // [kwave][gate][j][b]

  // --- persistent weight fragments: 7 gates x 2 kt, hi/lo bf16 split ---
  s16x8 whi[7][2], wlo[7][2];
  {
    const float* Wh = Wc + (size_t)(kE + kL) * kNC;
    const int colbase = jt * 16 + nl;
#pragma unroll
    for (int g = 0; g < 7; ++g) {
#pragma unroll
      for (int kt = 0; kt < 2; ++kt) {
        s16x8 hi, lo;
#pragma unroll
        for (int e = 0; e < 8; ++e) {
          const float w =
              Wh[(size_t)(wave * 64 + kt * 32 + kg * 8 + e) * kNC +
                 g * kH + colbase];
          const unsigned short h = f2bf(w);
          hi[e] = (short)h;
          lo[e] = (short)f2bf(w - bf2f(h));
        }
        whi[g][kt] = hi;
        wlo[g][kt] = lo;
      }
    }
  }

  // --- cooperative tagged-load assignment: 4 packets per thread ---
  const int t4 = tid * 4;                  // 0..2044
  const int b_ld = t4 >> 9;                // local batch 0..3
  const int k_ld = t4 & 511;
  unsigned int* ld_base =
      hdtag + (size_t)((bg * 4 + b_ld) * kH + k_ld) * 2;

  // --- pointwise lane state + rbias prefetch (wave 0 only) ---
  const int bl = lane >> 4;                // b_local for pointwise
  const int b_pw = bg * 4 + bl;
  const int j_pw = jt * 16 + nl;
  float c_d = 0.0f, c_bar = 0.0f, dtv = 0.0f;
  float rb[7];
#pragma unroll
  for (int m = 0; m < 7; ++m) rb[m] = 0.0f;
  if (wave == 0) {
    c_d = cd0[b_pw * kH + j_pw];
    c_bar = cb0[b_pw * kH + j_pw];
    const int mk = marks[b_pw * kT + 0];
    dtv = dt[b_pw * kT + 0];
#pragma unroll
    for (int m = 0; m < 7; ++m)
      rb[m] = emb_part[(size_t)mk * kNC + m * kH + j_pw] +
              lat_part[(size_t)b_pw * kNC + m * kH + j_pw];
  }

  // loop-carried poll registers (stay allocated while loads are in flight)
  u32x4 q0 = {0u, 0u, 0u, 0u};
  u32x4 q1 = {0u, 0u, 0u, 0u};

  for (int s = 1; s <= kT; ++s) {
    // ---- 1) pipelined tagged cooperative load ----
    const unsigned int tg = (unsigned int)(s - 1);
    unsigned int* lp = ld_base + (size_t)((s - 1) & 1) * (kBH * 2);

    // prologue: 4 idempotent rounds in flight (8 loads)
    asm volatile(
        "global_load_dwordx4 %0, %2, off sc0 sc1\n\t"
        "global_load_dwordx4 %1, %2, off offset:16 sc0 sc1\n\t"
        "global_load_dwordx4 %0, %2, off sc0 sc1\n\t"
        "global_load_dwordx4 %1, %2, off offset:16 sc0 sc1\n\t"
        "global_load_dwordx4 %0, %2, off sc0 sc1\n\t"
        "global_load_dwordx4 %1, %2, off offset:16 sc0 sc1\n\t"
        "global_load_dwordx4 %0, %2, off sc0 sc1\n\t"
        "global_load_dwordx4 %1, %2, off offset:16 sc0 sc1"
        : "+v"(q0), "+v"(q1) : "v"(lp) : "memory");
    for (;;) {
      asm volatile("s_waitcnt vmcnt(6)" ::: "memory");
      __builtin_amdgcn_sched_barrier(0);
      const bool ok =
          (q0[1] == tg) & (q0[3] == tg) & (q1[1] == tg) & (q1[3] == tg);
      if (__all(ok)) break;
      asm volatile(
          "global_load_dwordx4 %0, %2, off sc0 sc1\n\t"
          "global_load_dwordx4 %1, %2, off offset:16 sc0 sc1"
          : "+v"(q0), "+v"(q1) : "v"(lp) : "memory");
    }
    __builtin_amdgcn_sched_barrier(0);
    {
      u32x4 w = {q0[0], q0[2], q1[0], q1[2]};
      *(u32x4*)&lds_a[b_ld][k_ld] = w;
    }
    __syncthreads();

    // ---- 2) fragment reads + partial GEMM: 7 gates x (2 kt x 3-term) ----
    const unsigned int* ap = &lds_a[nl & 3][wave * 64 + kg * 8];
    u32x4 x0 = *(const u32x4*)(ap);
    u32x4 x1 = *(const u32x4*)(ap + 4);
    u32x4 x2 = *(const u32x4*)(ap + 32);
    u32x4 x3 = *(const u32x4*)(ap + 36);
    s16x8 ah0, al0, ah1, al1;
    unpack(x0, x1, ah0, al0);
    unpack(x2, x3, ah1, al1);

    f32x4 acc[7];
#pragma unroll
    for (int g = 0; g < 7; ++g) {
      f32x4 a = {0.0f, 0.0f, 0.0f, 0.0f};
      a = mfma_bf16(ah0, whi[g][0], a);
      a = mfma_bf16(ah0, wlo[g][0], a);
      a = mfma_bf16(al0, whi[g][0], a);
      a = mfma_bf16(ah1, whi[g][1], a);
      a = mfma_bf16(ah1, wlo[g][1], a);
      a = mfma_bf16(al1, whi[g][1], a);
      acc[g] = a;
    }
    if (lane < 16) {
#pragma unroll
      for (int g = 0; g < 7; ++g)
        *(f32x4*)&pl[wave][g][nl][0] = acc[g];
    }
    __syncthreads();

    // ---- 3) reduce + pointwise + publish (wave 0: 4 b x 16 j) ----
    if (wave == 0) {
      float g[7];
#pragma unroll
      for (int m = 0; m < 7; ++m) {
        float a = rb[m];
#pragma unroll
        for (int w = 0; w < 8; ++w) a += pl[w][m][nl][bl];
        g[m] = a;
      }
      const float gi = fsigmoid(g[0]);
      const float gf = fsigmoid(g[1]);
      const float gz = ftanh(g[2]);
      const float go = fsigmoid(g[3]);
      const float gib = fsigmoid(g[4]);
      const float gfb = fsigmoid(g[5]);
      const float gd = fsoftplus(g[6]);

      const float c = fmaf(gf, c_d, gi * gz);
      c_bar = fmaf(gfb, c_bar, gib * gz);
      c_d = c_bar + (c - c_bar) * fexp2(-gd * dtv * kLog2e);
      const float hd = go * ftanh(c_d);

      // fire-and-forget tagged publish (atomic 8B store, no ack wait)
      const unsigned int hh = f2bf(hd);
      const unsigned int hl = f2bf(hd - bf2f((unsigned short)hh));
      u32x2 pub = {hh | (hl << 16), (unsigned int)s};
      st_coh_x2(hdtag + (size_t)((s & 1) * kBH + b_pw * kH + j_pw) * 2, pub);

      float* orow = out + ((size_t)b_pw * (kT + 1) + s) * kOutRow;
      __builtin_nontemporal_store(hd, orow + j_pw);
      __builtin_nontemporal_store(go, orow + kH + j_pw);
      __builtin_nontemporal_store(c_bar, orow + 2 * kH + j_pw);
      __builtin_nontemporal_store(c, orow + 3 * kH + j_pw);
      __builtin_nontemporal_store(gd, orow + 4 * kH + j_pw);

      // prefetch next step's rbias/dt (off critical path)
      if (s < kT) {
        const int mk = marks[b_pw * kT + s];
        dtv = dt[b_pw * kT + s];
#pragma unroll
        for (int m = 0; m < 7; ++m)
          rb[m] = emb_part[(size_t)mk * kNC + m * kH + j_pw] +
                  lat_part[(size_t)b_pw * kNC + m * kH + j_pw];
      }
    }
  }

  // drain leftover pipelined loads before register reuse / kernel end
  asm volatile("s_waitcnt vmcnt(0)" ::: "memory");
  asm volatile("" :: "v"(q0), "v"(q1));
}

}  // namespace

extern "C" void kernel_launch(void* const* d_in, const int* in_sizes, int n_in,
                              void* d_out, int out_size, void* d_ws,
                              size_t ws_size, hipStream_t stream) {
  const int* marks = (const int*)d_in[0];
  const float* ts = (const float*)d_in[1];
  const float* latent = (const float*)d_in[2];
  const float* emb = (const float*)d_in[3];
  const float* Wc = (const float*)d_in[4];
  const float* bc = (const float*)d_in[5];
  const float* Wi = (const float*)d_in[6];
  const float* bi = (const float*)d_in[7];
  float* out = (float*)d_out;

  char* ws = (char*)d_ws;
  float* emb_part = (float*)(ws + 0);                 // 1,835,008 B
  float* lat_part = (float*)(ws + 1835008);           //   458,752 B
  float* dt       = (float*)(ws + 2293760);           //    65,536 B
  float* cd0      = (float*)(ws + 2359296);           //    65,536 B
  float* cb0      = (float*)(ws + 2424832);           //    65,536 B
  unsigned int* hdtag = (unsigned int*)(ws + 2490368); //  262,144 B

  hawkes_setup<<<286, 256, 0, stream>>>(ts, latent, emb, Wc, bc, Wi, bi, out,
                                        emb_part, lat_part, dt, cd0, cb0,
                                        hdtag);
  hawkes_seq<<<256, 512, 0, stream>>>(marks, Wc, out, emb_part, lat_part, dt,
                                      cd0, cb0, hdtag);
}

// Round 12
// 1527.827 us; speedup vs baseline: 1.7909x; 1.7909x over previous
//
#include <hip/hip_runtime.h>
#include <hip/hip_bf16.h>

namespace {

constexpr int kB = 32;
constexpr int kT = 512;
constexpr int kH = 512;
constexpr int kE = 256;
constexpr int kL = 64;
constexpr int kNC = 7 * kH;       // 3584 gate columns
constexpr int kOutRow = 5 * kH;   // 2560
constexpr int kBH = kB * kH;      // 16384 packets per parity slot

typedef float f32x4 __attribute__((ext_vector_type(4)));
typedef short s16x8 __attribute__((ext_vector_type(8)));
typedef __bf16 bf16x8 __attribute__((ext_vector_type(8)));
typedef unsigned int u32x4 __attribute__((ext_vector_type(4)));
typedef unsigned int u32x2 __attribute__((ext_vector_type(2)));

__device__ __forceinline__ unsigned short f2bf(float f) {
  __hip_bfloat16 h = __float2bfloat16(f);
  return __builtin_bit_cast(unsigned short, h);
}

__device__ __forceinline__ float bf2f(unsigned short u) {
  return __builtin_bit_cast(float, (unsigned int)u << 16);
}

// libm versions (setup only)
__device__ __forceinline__ float sigmoid_f(float x) {
  return 1.0f / (1.0f + expf(-x));
}
__device__ __forceinline__ float softplus_f(float x) {
  return fmaxf(x, 0.0f) + log1pf(expf(-fabsf(x)));
}

// fast versions (hot kernel): v_exp_f32 / v_log_f32 / v_rcp_f32
constexpr float kLog2e = 1.4426950408889634f;
constexpr float kLn2 = 0.6931471805599453f;
__device__ __forceinline__ float fexp2(float x) {
  return __builtin_amdgcn_exp2f(x);
}
__device__ __forceinline__ float frcp(float x) {
  return __builtin_amdgcn_rcpf(x);
}
__device__ __forceinline__ float fsigmoid(float x) {
  return frcp(1.0f + fexp2(-x * kLog2e));
}
__device__ __forceinline__ float ftanh(float x) {
  return 1.0f - 2.0f * frcp(1.0f + fexp2((2.0f * kLog2e) * x));
}
__device__ __forceinline__ float fsoftplus(float x) {
  return fmaxf(x, 0.0f) +
         kLn2 * __builtin_amdgcn_logf(1.0f + fexp2(-fabsf(x) * kLog2e));
}

__device__ __forceinline__ f32x4 mfma_bf16(s16x8 a, s16x8 b, f32x4 c) {
  return __builtin_amdgcn_mfma_f32_16x16x32_bf16(
      __builtin_bit_cast(bf16x8, a), __builtin_bit_cast(bf16x8, b), c, 0, 0, 0);
}

__device__ __forceinline__ void st_coh_x2(unsigned int* p, u32x2 v) {
  asm volatile("global_store_dwordx2 %0, %1, off sc0 sc1" :: "v"(p), "v"(v)
               : "memory");
}

__device__ __forceinline__ void unpack(const u32x4& x0, const u32x4& x1,
                                       s16x8& hi, s16x8& lo) {
#pragma unroll
  for (int e = 0; e < 4; ++e) {
    hi[e] = (short)(x0[e] & 0xffffu);
    hi[e + 4] = (short)(x1[e] & 0xffffu);
    lo[e] = (short)(x0[e] >> 16);
    lo[e + 4] = (short)(x1[e] >> 16);
  }
}

// ---------------------------------------------------------------------------
// Setup: emb_part [128][3584], lat_part(+bias) [32][3584], dt [32][512],
// init states -> out row 0, hdtag parity0 = {h0, tag 0}, parity1 poisoned.
// ---------------------------------------------------------------------------
__global__ void hawkes_setup(const float* __restrict__ ts,
                             const float* __restrict__ latent,
                             const float* __restrict__ emb,
                             const float* __restrict__ Wc,
                             const float* __restrict__ bc,
                             const float* __restrict__ Wi,
                             const float* __restrict__ bi,
                             float* __restrict__ out,
                             float* __restrict__ emb_part,
                             float* __restrict__ lat_part,
                             float* __restrict__ dt,
                             float* __restrict__ cd0,
                             float* __restrict__ cb0,
                             unsigned int* __restrict__ hdtag) {
  const int blk = blockIdx.x;
  const int tid = threadIdx.x;
  if (blk < 112) {
    __shared__ float es[16][kE];
    const int cgrp = blk / 14;
    const int col = (blk % 14) * 256 + tid;
    for (int i = tid; i < 16 * kE; i += 256)
      es[i / kE][i % kE] = emb[(cgrp * 16 + i / kE) * kE + (i % kE)];
    __syncthreads();
    float acc[16];
#pragma unroll
    for (int c = 0; c < 16; ++c) acc[c] = 0.0f;
    for (int e = 0; e < kE; ++e) {
      const float w = Wc[(size_t)e * kNC + col];
#pragma unroll
      for (int c = 0; c < 16; ++c) acc[c] = fmaf(es[c][e], w, acc[c]);
    }
#pragma unroll
    for (int c = 0; c < 16; ++c)
      emb_part[(size_t)(cgrp * 16 + c) * kNC + col] = acc[c];
  } else if (blk < 126) {
    __shared__ float ls[kB][kL];
    const int col = (blk - 112) * 256 + tid;
    for (int i = tid; i < kB * kL; i += 256) ls[i / kL][i % kL] = latent[i];
    __syncthreads();
    float acc[kB];
    const float bias = bc[col];
#pragma unroll
    for (int b = 0; b < kB; ++b) acc[b] = bias;
    for (int l = 0; l < kL; ++l) {
      const float w = Wc[(size_t)(kE + l) * kNC + col];
#pragma unroll
      for (int b = 0; b < kB; ++b) acc[b] = fmaf(ls[b][l], w, acc[b]);
    }
#pragma unroll
    for (int b = 0; b < kB; ++b) lat_part[(size_t)b * kNC + col] = acc[b];
  } else if (blk < 222) {
    const int tg = (blk - 126) * 256 + tid;
    for (int it = 0; it < 4; ++it) {
      const int item = tg + it * 24576;
      const int b = item / 3072;
      const int c6 = item % 3072;
      float a = bi[c6];
      for (int l = 0; l < kL; ++l)
        a = fmaf(latent[b * kL + l], Wi[(size_t)l * 3072 + c6], a);
      const int which = c6 >> 9;
      const int jl = c6 & 511;
      float* orow = out + (size_t)b * (kT + 1) * kOutRow;
      if (which == 0) {
        const float h = tanhf(a);
        orow[jl] = h;
        const unsigned int hh = f2bf(h);
        const unsigned int hl = f2bf(h - bf2f((unsigned short)hh));
        u32x2 v0 = {hh | (hl << 16), 0u};
        u32x2 v1 = {0u, 0xFFFFFFFFu};
        st_coh_x2(hdtag + (size_t)(b * kH + jl) * 2, v0);
        st_coh_x2(hdtag + (size_t)(kBH + b * kH + jl) * 2, v1);
      } else if (which == 1) {
        cd0[b * kH + jl] = tanhf(a);
      } else if (which == 2) {
        const float v = tanhf(a);
        orow[2 * kH + jl] = v;
        cb0[b * kH + jl] = v;
      } else if (which == 3) {
        orow[3 * kH + jl] = tanhf(a);
      } else if (which == 4) {
        orow[4 * kH + jl] = softplus_f(a);
      } else {
        orow[kH + jl] = sigmoid_f(a);
      }
    }
  } else {
    const int idx = (blk - 222) * 256 + tid;   // [0,16384)
    const int b = idx >> 9;
    const int t = idx & 511;
    dt[idx] = (t == 0) ? ts[b * kT] : ts[b * kT + t] - ts[b * kT + t - 1];
  }
}

// ---------------------------------------------------------------------------
// Sequential scan (R3-proven exchange + per-wave self-load, no B1):
// 256 blocks = 8 batch-groups (4 batches) x 32 hidden-tiles (16 units).
// 8 waves x 64; wave w owns k-slice [w*64,w*64+64) (weights persistent,
// bf16 hi/lo, 3-term MFMA). Per step:
//   1) wave w loads ITS OWN fragment region [4 batches]x[64 k] of tagged
//      packets (fused poll==data, s_sleep backoff) -> its own lds_a region.
//      LDS write + fragment read are same-wave -> lgkmcnt(0) only, NO
//      block barrier: each wave starts MFMA as soon as ITS slice arrives
//      (detect jitter overlaps MFMA instead of block-wide max).
//   2) 42 MFMAs; partials -> pl; __syncthreads (B2).
//   3) wave0: reduce, pointwise, publish {h_d, tag=s} fire-and-forget,
//      out-stores + next-step rbias prefetch (off critical path).
// ---------------------------------------------------------------------------
__global__ __launch_bounds__(512, 2) void hawkes_seq(
    const int* __restrict__ marks, const float* __restrict__ Wc,
    float* __restrict__ out, const float* __restrict__ emb_part,
    const float* __restrict__ lat_part, const float* __restrict__ dt,
    const float* __restrict__ cd0, const float* __restrict__ cb0,
    unsigned int* __restrict__ hdtag) {
  const int blk = blockIdx.x;
  const int bg = blk >> 5;                 // batch group 0..7
  const int jt = blk & 31;                 // hidden tile 0..31
  const int tid = threadIdx.x;
  const int wave = tid >> 6;               // k-slice 0..7
  const int lane = tid & 63;
  const int nl = lane & 15;                // fragment column / A row
  const int kg = lane >> 4;                // k-subgroup 0..3

  __shared__ __align__(16) unsigned int lds_a[4][516];  // packed hi|lo, pad 4
  __shared__ float pl[8][7][16][4];                     // [kwave][gate][j][b]

  // --- persistent weight fragments: 7 gates x 2 kt, hi/lo bf16 split ---
  s16x8 whi[7][2], wlo[7][2];
  {
    const float* Wh = Wc + (size_t)(kE + kL) * kNC;
    const int colbase = jt * 16 + nl;
#pragma unroll
    for (int g = 0; g < 7; ++g) {
#pragma unroll
      for (int kt = 0; kt < 2; ++kt) {
        s16x8 hi, lo;
#pragma unroll
        for (int e = 0; e < 8; ++e) {
          const float w =
              Wh[(size_t)(wave * 64 + kt * 32 + kg * 8 + e) * kNC +
                 g * kH + colbase];
          const unsigned short h = f2bf(w);
          hi[e] = (short)h;
          lo[e] = (short)f2bf(w - bf2f(h));
        }
        whi[g][kt] = hi;
        wlo[g][kt] = lo;
      }
    }
  }

  // --- per-wave self-load assignment: wave w covers [4 b] x [64 k] ---
  const int b_ld = lane >> 4;              // local batch 0..3
  const int k_ld = wave * 64 + (lane & 15) * 4;
  unsigned int* ld_base =
      hdtag + (size_t)((bg * 4 + b_ld) * kH + k_ld) * 2;

  // --- pointwise lane state + rbias prefetch (wave 0 only) ---
  const int bl = lane >> 4;                // b_local for pointwise
  const int b_pw = bg * 4 + bl;
  const int j_pw = jt * 16 + nl;
  float c_d = 0.0f, c_bar = 0.0f, dtv = 0.0f;
  float rb[7];
#pragma unroll
  for (int m = 0; m < 7; ++m) rb[m] = 0.0f;
  if (wave == 0) {
    c_d = cd0[b_pw * kH + j_pw];
    c_bar = cb0[b_pw * kH + j_pw];
    const int mk = marks[b_pw * kT + 0];
    dtv = dt[b_pw * kT + 0];
#pragma unroll
    for (int m = 0; m < 7; ++m)
      rb[m] = emb_part[(size_t)mk * kNC + m * kH + j_pw] +
              lat_part[(size_t)b_pw * kNC + m * kH + j_pw];
  }

  for (int s = 1; s <= kT; ++s) {
    // ---- 1) per-wave tagged self-load (poll == data, sleep backoff) ----
    const unsigned int tg = (unsigned int)(s - 1);
    unsigned int* lp = ld_base + (size_t)((s - 1) & 1) * (kBH * 2);
    u32x4 d0, d1;
    for (;;) {
      asm volatile(
          "global_load_dwordx4 %0, %2, off sc0 sc1\n\t"
          "global_load_dwordx4 %1, %2, off offset:16 sc0 sc1\n\t"
          "s_waitcnt vmcnt(0)"
          : "=v"(d0), "=v"(d1) : "v"(lp) : "memory");
      if (d0[1] == tg && d0[3] == tg && d1[1] == tg && d1[3] == tg) break;
      asm volatile("s_sleep 2" ::: "memory");   // ~128 cy off the fabric
    }
    {
      u32x4 w = {d0[0], d0[2], d1[0], d1[2]};
      *(u32x4*)&lds_a[b_ld][k_ld] = w;
    }
    // same-wave LDS visibility only: NO block barrier (B1 removed)
    __builtin_amdgcn_sched_barrier(0);
    asm volatile("s_waitcnt lgkmcnt(0)" ::: "memory");
    __builtin_amdgcn_sched_barrier(0);

    // ---- 2) fragment reads + partial GEMM: 7 gates x (2 kt x 3-term) ----
    const unsigned int* ap = &lds_a[nl & 3][wave * 64 + kg * 8];
    u32x4 x0 = *(const u32x4*)(ap);
    u32x4 x1 = *(const u32x4*)(ap + 4);
    u32x4 x2 = *(const u32x4*)(ap + 32);
    u32x4 x3 = *(const u32x4*)(ap + 36);
    s16x8 ah0, al0, ah1, al1;
    unpack(x0, x1, ah0, al0);
    unpack(x2, x3, ah1, al1);

    f32x4 acc[7];
#pragma unroll
    for (int g = 0; g < 7; ++g) {
      f32x4 a = {0.0f, 0.0f, 0.0f, 0.0f};
      a = mfma_bf16(ah0, whi[g][0], a);
      a = mfma_bf16(ah0, wlo[g][0], a);
      a = mfma_bf16(al0, whi[g][0], a);
      a = mfma_bf16(ah1, whi[g][1], a);
      a = mfma_bf16(ah1, wlo[g][1], a);
      a = mfma_bf16(al1, whi[g][1], a);
      acc[g] = a;
    }
    if (lane < 16) {
#pragma unroll
      for (int g = 0; g < 7; ++g)
        *(f32x4*)&pl[wave][g][nl][0] = acc[g];
    }
    __syncthreads();                        // B2

    // ---- 3) reduce + pointwise + publish (wave 0: 4 b x 16 j) ----
    if (wave == 0) {
      float g[7];
#pragma unroll
      for (int m = 0; m < 7; ++m) {
        float a = rb[m];
#pragma unroll
        for (int w = 0; w < 8; ++w) a += pl[w][m][nl][bl];
        g[m] = a;
      }
      const float gi = fsigmoid(g[0]);
      const float gf = fsigmoid(g[1]);
      const float gz = ftanh(g[2]);
      const float go = fsigmoid(g[3]);
      const float gib = fsigmoid(g[4]);
      const float gfb = fsigmoid(g[5]);
      const float gd = fsoftplus(g[6]);

      const float c = fmaf(gf, c_d, gi * gz);
      c_bar = fmaf(gfb, c_bar, gib * gz);
      c_d = c_bar + (c - c_bar) * fexp2(-gd * dtv * kLog2e);
      const float hd = go * ftanh(c_d);

      // fire-and-forget tagged publish (atomic 8B store, no ack wait)
      const unsigned int hh = f2bf(hd);
      const unsigned int hl = f2bf(hd - bf2f((unsigned short)hh));
      u32x2 pub = {hh | (hl << 16), (unsigned int)s};
      st_coh_x2(hdtag + (size_t)((s & 1) * kBH + b_pw * kH + j_pw) * 2, pub);

      float* orow = out + ((size_t)b_pw * (kT + 1) + s) * kOutRow;
      __builtin_nontemporal_store(hd, orow + j_pw);
      __builtin_nontemporal_store(go, orow + kH + j_pw);
      __builtin_nontemporal_store(c_bar, orow + 2 * kH + j_pw);
      __builtin_nontemporal_store(c, orow + 3 * kH + j_pw);
      __builtin_nontemporal_store(gd, orow + 4 * kH + j_pw);

      // prefetch next step's rbias/dt (off critical path)
      if (s < kT) {
        const int mk = marks[b_pw * kT + s];
        dtv = dt[b_pw * kT + s];
#pragma unroll
        for (int m = 0; m < 7; ++m)
          rb[m] = emb_part[(size_t)mk * kNC + m * kH + j_pw] +
                  lat_part[(size_t)b_pw * kNC + m * kH + j_pw];
      }
    }
  }
}

}  // namespace

extern "C" void kernel_launch(void* const* d_in, const int* in_sizes, int n_in,
                              void* d_out, int out_size, void* d_ws,
                              size_t ws_size, hipStream_t stream) {
  const int* marks = (const int*)d_in[0];
  const float* ts = (const float*)d_in[1];
  const float* latent = (const float*)d_in[2];
  const float* emb = (const float*)d_in[3];
  const float* Wc = (const float*)d_in[4];
  const float* bc = (const float*)d_in[5];
  const float* Wi = (const float*)d_in[6];
  const float* bi = (const float*)d_in[7];
  float* out = (float*)d_out;

  char* ws = (char*)d_ws;
  float* emb_part = (float*)(ws + 0);                 // 1,835,008 B
  float* lat_part = (float*)(ws + 1835008);           //   458,752 B
  float* dt       = (float*)(ws + 2293760);           //    65,536 B
  float* cd0      = (float*)(ws + 2359296);           //    65,536 B
  float* cb0      = (float*)(ws + 2424832);           //    65,536 B
  unsigned int* hdtag = (unsigned int*)(ws + 2490368); //  262,144 B

  hawkes_setup<<<286, 256, 0, stream>>>(ts, latent, emb, Wc, bc, Wi, bi, out,
                                        emb_part, lat_part, dt, cd0, cb0,
                                        hdtag);
  hawkes_seq<<<256, 512, 0, stream>>>(marks, Wc, out, emb_part, lat_part, dt,
                                      cd0, cb0, hdtag);
}